// Round 2
// 707.496 us; speedup vs baseline: 1.0595x; 1.0595x over previous
//
#include <hip/hip_runtime.h>

// SuperpixelPooling: per-(batch, superpixel) mean of 64-dim feature vectors.
// feat[8,512,512,64] f32, labels[8,512,512] i32 in [0,256) -> out[8,256,64] f32.
//
// Round-4 design: zero atomics (kept from r3), but the gather is now
// MLP-batched. r3 measured 750 us vs ~85 us roofline because each matched
// pixel was one serialized 256 B wave-load (1 outstanding load/wave ->
// latency-bound, ~0.5 MB in flight vs the ~2.4 MB Little's-law requirement).
//
// New structure:
//   scan:  int4 label chunks + __ballot; matched pixel indices (wave-uniform
//          scalars) are PUSHED into a per-wave LDS ring queue (no mem wait).
//   drain: when 16 entries queue up, gather them as 4 pixels per wave
//          instruction (lane = [pixel-slot 0..3][channel-group 0..15],
//          float4/lane) -> 4 independent 1 KB loads issued back-to-back,
//          ONE vmcnt wait per 16 pixels (4 KB in flight per wave).
//   end:   tail-drain (<16 entries, sentinel-padded), then cross-slot
//          __shfl_xor(16/32) folds the 4 pixel-slots into channel sums.
//
// Counts come from ballot popcounts as before. Features read exactly once
// (512 MB HBM); labels are L2-resident (1 MB/batch, re-read 128x).

#define NBATCH 8
#define NSEG 256
#define NCH 64
#define PPB (512 * 512)        // 262144 pixels per batch
#define GSEG 2                 // segments owned per block
#define NWAVE 8                // 512 threads
#define PIX_PER_WAVE (PPB / NWAVE)          // 32768
#define ITERS (PIX_PER_WAVE / (64 * 4))     // 128 int4-iterations per wave
#define QCAP 32                // ring capacity (power of 2, > DRAIN_AT)
#define DRAIN_AT 16            // drain threshold: 16 pixels = 4 x 1KB loads

__global__ __launch_bounds__(512, 8) void pool_kernel(const float* __restrict__ feat,
                                                      const int* __restrict__ sp,
                                                      float* __restrict__ out) {
    __shared__ float part[NWAVE][GSEG][NCH];   // 4 KB
    __shared__ unsigned scnt[NWAVE][GSEG];
    __shared__ int q[NWAVE][GSEG][QCAP];       // 2 KB ring queues

    const int b = blockIdx.x >> 7;             // 1024 blocks: batch = idx/128
    const int sgrp = blockIdx.x & 127;         // segment pair
    const int seg0 = sgrp * 2;
    const int seg1 = seg0 + 1;
    const int lane = threadIdx.x & 63;
    const int wave = threadIdx.x >> 6;
    const int slot = lane >> 4;                // pixel slot within a burst (0..3)
    const int chg  = lane & 15;                // channel group (4 ch each)

    const int4* lp4 = (const int4*)(sp + (size_t)b * PPB + (size_t)wave * PIX_PER_WAVE);
    const float4* fb4 = (const float4*)(feat + (size_t)b * PPB * NCH);

    float4 acc0 = {0.f, 0.f, 0.f, 0.f};
    float4 acc1 = {0.f, 0.f, 0.f, 0.f};
    unsigned c0 = 0u, c1 = 0u;
    int h0 = 0, t0 = 0, h1 = 0, t1 = 0;        // ring head/tail (wave-uniform)

    int* q0 = q[wave][0];
    int* q1 = q[wave][1];

    // Drain exactly 16 queued pixels: 4 bursts of 4 pixels. Lane (slot,chg)
    // loads float4 #chg of pixel #(H+k*4+slot). 4 independent global loads
    // issued before any consumer -> one latency stall per 16 pixels.
#define DRAIN16(QP, H, ACC)                                                   \
    do {                                                                      \
        int p0_ = QP[(H + 0  + slot) & (QCAP - 1)];                           \
        int p1_ = QP[(H + 4  + slot) & (QCAP - 1)];                           \
        int p2_ = QP[(H + 8  + slot) & (QCAP - 1)];                           \
        int p3_ = QP[(H + 12 + slot) & (QCAP - 1)];                           \
        float4 v0_ = fb4[(size_t)p0_ * 16 + chg];                             \
        float4 v1_ = fb4[(size_t)p1_ * 16 + chg];                             \
        float4 v2_ = fb4[(size_t)p2_ * 16 + chg];                             \
        float4 v3_ = fb4[(size_t)p3_ * 16 + chg];                             \
        ACC.x += (v0_.x + v1_.x) + (v2_.x + v3_.x);                           \
        ACC.y += (v0_.y + v1_.y) + (v2_.y + v3_.y);                           \
        ACC.z += (v0_.z + v1_.z) + (v2_.z + v3_.z);                           \
        ACC.w += (v0_.w + v1_.w) + (v2_.w + v3_.w);                           \
        H += 16;                                                              \
    } while (0)

    int4 cur = lp4[lane];                      // prefetch chunk 0
    for (int i = 0; i < ITERS; ++i) {
        const int ni = (i + 1 < ITERS) ? (i + 1) : i;
        int4 nxt = lp4[ni * 64 + lane];
        const int base = wave * PIX_PER_WAVE + i * 256;  // batch-local pixel base

        // process 4 label components; pixel(bit j, comp c) = base + j*4 + c
#define PROC(LV, C)                                                          \
        {                                                                    \
            unsigned long long m0_ = __ballot((LV) == seg0);                 \
            unsigned long long m1_ = __ballot((LV) == seg1);                 \
            c0 += (unsigned)__builtin_popcountll(m0_);                       \
            c1 += (unsigned)__builtin_popcountll(m1_);                       \
            while (m0_) {                                                    \
                int j = __builtin_ctzll(m0_); m0_ &= m0_ - 1;                \
                q0[t0 & (QCAP - 1)] = base + j * 4 + (C); t0++;              \
                if (t0 - h0 >= DRAIN_AT) DRAIN16(q0, h0, acc0);              \
            }                                                                \
            while (m1_) {                                                    \
                int j = __builtin_ctzll(m1_); m1_ &= m1_ - 1;                \
                q1[t1 & (QCAP - 1)] = base + j * 4 + (C); t1++;              \
                if (t1 - h1 >= DRAIN_AT) DRAIN16(q1, h1, acc1);              \
            }                                                                \
        }
        PROC(cur.x, 0)
        PROC(cur.y, 1)
        PROC(cur.z, 2)
        PROC(cur.w, 3)
#undef PROC
        cur = nxt;
    }

    // Tail drain: < DRAIN_AT entries per queue, 4 pixels at a time,
    // sentinel (-1) padded. Per-slot predication only.
#define TAIL(QP, H, T, ACC)                                                   \
    while (H < T) {                                                           \
        int p_ = (H + slot < T) ? QP[(H + slot) & (QCAP - 1)] : -1;           \
        if (p_ >= 0) {                                                        \
            float4 v_ = fb4[(size_t)p_ * 16 + chg];                           \
            ACC.x += v_.x; ACC.y += v_.y; ACC.z += v_.z; ACC.w += v_.w;       \
        }                                                                     \
        H += 4;                                                               \
    }
    TAIL(q0, h0, t0, acc0)
    TAIL(q1, h1, t1, acc1)
#undef TAIL
#undef DRAIN16

    // Fold the 4 pixel-slots: lanes slot*16+chg hold partial channel sums for
    // channels [4*chg, 4*chg+4). xor-reduce over lane bits 4 and 5.
    acc0.x += __shfl_xor(acc0.x, 16); acc0.x += __shfl_xor(acc0.x, 32);
    acc0.y += __shfl_xor(acc0.y, 16); acc0.y += __shfl_xor(acc0.y, 32);
    acc0.z += __shfl_xor(acc0.z, 16); acc0.z += __shfl_xor(acc0.z, 32);
    acc0.w += __shfl_xor(acc0.w, 16); acc0.w += __shfl_xor(acc0.w, 32);
    acc1.x += __shfl_xor(acc1.x, 16); acc1.x += __shfl_xor(acc1.x, 32);
    acc1.y += __shfl_xor(acc1.y, 16); acc1.y += __shfl_xor(acc1.y, 32);
    acc1.z += __shfl_xor(acc1.z, 16); acc1.z += __shfl_xor(acc1.z, 32);
    acc1.w += __shfl_xor(acc1.w, 16); acc1.w += __shfl_xor(acc1.w, 32);

    if (lane < 16) {                           // slot==0 lanes: chg == lane
        ((float4*)part[wave][0])[lane] = acc0;
        ((float4*)part[wave][1])[lane] = acc1;
    }
    if (lane == 0) { scnt[wave][0] = c0; scnt[wave][1] = c1; }
    __syncthreads();

    if (threadIdx.x < GSEG * NCH) {            // 128 threads: g = tid/64
        const int g = threadIdx.x >> 6;
        const int l = threadIdx.x & 63;
        float s = 0.0f;
        unsigned cn = 0u;
#pragma unroll
        for (int w = 0; w < NWAVE; ++w) {
            s += part[w][g][l];
            cn += scnt[w][g];
        }
        const size_t orow = (size_t)b * NSEG + (size_t)(seg0 + g);
        out[orow * NCH + l] = s / (float)(cn > 0u ? cn : 1u);
    }
}

extern "C" void kernel_launch(void* const* d_in, const int* in_sizes, int n_in,
                              void* d_out, int out_size, void* d_ws, size_t ws_size,
                              hipStream_t stream) {
    const float* feat = (const float*)d_in[0];
    const int* sp = (const int*)d_in[1];
    float* out = (float*)d_out;
    (void)d_ws; (void)ws_size;

    pool_kernel<<<NBATCH * (NSEG / GSEG), 512, 0, stream>>>(feat, sp, out);
}